// Round 8
// baseline (203.434 us; speedup 1.0000x reference)
//
#include <hip/hip_runtime.h>
#include <math.h>

// Turb2dPDE, MFMA fp16-split pipeline. Per batch:
//   Y = x * C2; Out = F1 * Y; X = streams x G; psiT = Hc x X; then stencil.
// R1: 512-thread blocks.  R2/R3: SGPR addressing, const-offset stencil.
// R4: S32 restride->b128, Se dwordx4 layout.
// R6: two batches per block (grid 2048, LDS 80896, 2 blocks/CU); barriers/batch
//     6->2.5; shared table frags. 99->90us. R7 (NB=4, 1 block/CU) REGRESSED to
//     110us: barrier drains need a co-resident block to overlap with.
// R8: R6 structure with 1024-THREAD BLOCKS (16 waves). Same 2 blocks/CU, same
//     batches/CU, same drain count -- but every stage's per-wave critical path
//     halves. Discriminates stage-critical-path-bound (expect ~75us) from
//     issue-bound (expect flat 90us -> next lever is instruction count).

typedef _Float16 half8 __attribute__((ext_vector_type(8)));
typedef _Float16 half4 __attribute__((ext_vector_type(4)));
typedef float floatx4 __attribute__((ext_vector_type(4)));

#define WPI 0.09666439165562847f   // 2*pi/65

// half-unit offsets in ws
#define H_TB1 0        // [20 chunks][512] S1-B
#define H_TA2 10240    // [20 chunks][512] S2-A
#define H_TG  20480    // [12 chunks][512] S4a-B
#define H_TH  26624    // [12 chunks][512] S4b-A
// float-unit offsets
#define F_GR32 16384
#define F_GI32 16432
#define F_HC32 16480
#define F_HS32 16528
#define F_SE   16576   // [8][33] jj=32 col, then [8][33][32] grid
#define F_SEG  (F_SE + 264)

// per-batch LDS arena offsets (bytes), arena t at lds_raw + t*40448
#define ARENA 40448
#define NB 2
#define OFF_YT   0
#define OFF_XR   0
#define OFF_XI   9216
#define OFF_X32R 18432
#define OFF_X32I 18688
#define OFF_ST   18944
#define OFF_S32  37952      // [4][36] f32
#define OFF_PSIT 18944

__device__ __forceinline__ float trig65(int t, int isSin) {
    return isSin ? __sinf(WPI * (float)t) : __cosf(WPI * (float)t);
}

__global__ void setup_tables(float* __restrict__ ws, const float* __restrict__ domain) {
    int idx = blockIdx.x * 256 + threadIdx.x;
    _Float16* tbH = (_Float16*)ws;
    const float inv = 1.0f / 4225.0f;
    if (idx < 32768) {
        float v = 0.0f;
        int part;
        if (idx < 10240) {                  // TB1 (B-layout): chunk=(ni*2+kc)*2+part
            int chunk = idx >> 9, within = idx & 511;
            part = chunk & 1; int kc = (chunk >> 1) & 1, ni = chunk >> 2;
            int l2 = within >> 3, j = within & 7;
            int row = 16 * ni + (l2 & 15);
            int k = 32 * kc + 8 * (l2 >> 4) + j;
            if (row < 66) {
                int c = (row < 32) ? row : (row < 64 ? row - 32 : 32);
                int isS = (row < 32) ? 0 : (row < 64 ? 1 : row - 64);
                v = trig65((k * c) % 65, isS);
                if (k == 0) v += trig65((64 * c) % 65, isS);
            }
        } else if (idx < 20480) {           // TA2 (A-layout): chunk=(mi*2+kc)*2+part
            int i2 = idx - 10240;
            int chunk = i2 >> 9, within = i2 & 511;
            part = chunk & 1; int kc = (chunk >> 1) & 1, mi = chunk >> 2;
            int l2 = within >> 3, j = within & 7;
            int row = 16 * mi + (l2 & 15);
            int m = 32 * kc + 8 * (l2 >> 4) + j;
            if (row < 66) {
                int jr = (row < 32) ? row : (row < 64 ? row - 32 : 32);
                int isS = (row < 32) ? 0 : (row < 64 ? 1 : row - 64);
                float s = isS ? 1.0f : -1.0f;   // P rows = -cos, Q rows = +sin
                v = s * trig65((jr * m) % 65, isS);
                if (m == 0) v += s * trig65((jr * 64) % 65, isS);
            }
        } else if (idx < 26624) {           // TG: chunk=(si*2+g)*2+part
            int i2 = idx - 20480;
            int chunk = i2 >> 9, within = i2 & 511;
            part = chunk & 1; int g = (chunk >> 1) & 1, si = chunk >> 2;
            int l2 = within >> 3, j = within & 7;
            int s = 16 * si + (l2 & 15);
            int jj = 8 * (l2 >> 4) + j;
            if (s <= 32) v = trig65((s * jj) % 65, g);
        } else {                            // TH: chunk=(pi*2+h)*2+part
            int i2 = idx - 26624;
            int chunk = i2 >> 9, within = i2 & 511;
            part = chunk & 1; int h = (chunk >> 1) & 1, pi2 = chunk >> 2;
            int l2 = within >> 3, j = within & 7;
            int p = 16 * pi2 + (l2 & 15);
            int c = 8 * (l2 >> 4) + j;
            if (p <= 32) {
                if (c == 0) v = h ? 0.0f : inv;
                else v = 2.0f * inv * trig65((c * p) % 65, h);
            }
        }
        _Float16 hh = (_Float16)v;
        tbH[idx] = part ? (_Float16)(v - (float)hh) : hh;
    } else if (idx < 32960) {               // fp32 aux
        int i2 = idx - 32768;
        int grp = i2 / 48, s = i2 - grp * 48;
        float v = 0.0f;
        if (s <= 32) {
            int t = (32 * s) % 65;
            float cs = __cosf(WPI * t), sn = __sinf(WPI * t);
            v = (grp == 0) ? cs : (grp == 1) ? sn : (grp == 2) ? 2.0f * inv * cs : 2.0f * inv * sn;
        }
        ws[F_GR32 + i2] = v;
    } else if (idx < 41672) {               // Se
        int i2 = idx - 32960;
        const float DX0 = 0.04908738521234052f;
        int e2, a, b2;
        if (i2 < 264) { e2 = i2 / 33; a = i2 - e2 * 33; b2 = 32; }
        else {
            int i3 = i2 - 264;
            e2 = i3 / 1056;
            int rem = i3 - e2 * 1056;
            a = rem >> 5; b2 = rem & 31;
        }
        float fdx = domain[e2] * DX0;
        float tt = 6.283185307179586f / (65.0f * fdx);
        float s2v = tt * tt;
        ws[F_SE + i2] = -1.0f / (1e-12f + s2v * (float)(a * a + b2 * b2));
    }
}

#define MFMA16(A, B, C) __builtin_amdgcn_mfma_f32_16x16x32_f16((A), (B), (C), 0, 0, 0)

__global__ __launch_bounds__(1024, 4)
void turb_kernel(const float* __restrict__ y0, const int* __restrict__ env,
                 const float* __restrict__ params, const float* __restrict__ domain,
                 const float* __restrict__ ws, float* __restrict__ out) {
    __shared__ __align__(16) char lds_raw[NB * ARENA];   // 80896 B -> 2 blocks/CU

    const int b0 = blockIdx.x * NB, tid = threadIdx.x;
    const int wid = __builtin_amdgcn_readfirstlane(tid >> 6);   // 0..15
    const int lane = tid & 63, n16 = lane & 15, q = lane >> 4;
    const int lane8 = lane * 8;
    const _Float16* tbH = (const _Float16*)ws;
    const float* tf = ws;

    // per-batch scalars
    int eA[NB];
    const float *SegA[NB], *Se3A[NB], *xA[NB];
    float* outA[NB];
    float invfA[NB], inv12A[NB];
    const float DX0 = 0.04908738521234052f;
    #pragma unroll
    for (int t = 0; t < NB; t++) {
        eA[t] = __builtin_amdgcn_readfirstlane(env[b0 + t]);
        SegA[t] = tf + F_SEG + eA[t] * 1056;
        Se3A[t] = tf + F_SE + eA[t] * 33;
        xA[t]   = y0 + (size_t)(b0 + t) * 4096;
        outA[t] = out + (size_t)(b0 + t) * 4096;
        float mu = params[2 * eA[t]];
        float f = domain[eA[t]] * DX0, f2 = f * f;
        inv12A[t] = 1.0f / (12.0f * f2);
        invfA[t] = mu / f2;
    }

    // ---- S1: Yt[c'][m] = sum_k x[m][k]*TB1[c'][k], both batches per position
    // 16 waves: mi = wid&3; g1 = wid>>2 selects ni set {0,1} | {2} | {3} | {4}.
    {
        const int mi = wid & 3;
        const int g1 = wid >> 2;
        half8 Ah[NB][2], Al[NB][2];
        #pragma unroll
        for (int t = 0; t < NB; t++) {
            const float* xrow = xA[t] + (16 * mi + n16) * 64 + 8 * q;
            #pragma unroll
            for (int kc = 0; kc < 2; kc++) {
                float4 v0 = *(const float4*)(xrow + 32 * kc);
                float4 v1 = *(const float4*)(xrow + 32 * kc + 4);
                float vv[8] = {v0.x, v0.y, v0.z, v0.w, v1.x, v1.y, v1.z, v1.w};
                #pragma unroll
                for (int u = 0; u < 8; u++) {
                    _Float16 h = (_Float16)vv[u];
                    Ah[t][kc][u] = h; Al[t][kc][u] = (_Float16)(vv[u] - (float)h);
                }
            }
        }
        const int niBeg = (g1 == 0) ? 0 : g1 + 1;
        const int niEnd = (g1 == 0) ? 2 : g1 + 2;
        for (int ni = niBeg; ni < niEnd; ni++) {
            const _Float16* tb = tbH + H_TB1 + ni * 2048 + lane8;
            half8 B0h = *(const half8*)(tb);
            half8 B0l = *(const half8*)(tb + 512);
            half8 B1h = *(const half8*)(tb + 1024);
            half8 B1l = *(const half8*)(tb + 1536);
            const int cp = 16 * ni + n16;
            const bool st = (ni < 4 || n16 < 2);
            #pragma unroll
            for (int t = 0; t < NB; t++) {
                floatx4 acc = {0.f, 0.f, 0.f, 0.f};
                acc = MFMA16(Ah[t][0], B0h, acc); acc = MFMA16(Ah[t][0], B0l, acc); acc = MFMA16(Al[t][0], B0h, acc);
                acc = MFMA16(Ah[t][1], B1h, acc); acc = MFMA16(Ah[t][1], B1l, acc); acc = MFMA16(Al[t][1], B1h, acc);
                if (st) {
                    half4 hh, ll;
                    #pragma unroll
                    for (int i = 0; i < 4; i++) {
                        _Float16 h = (_Float16)acc[i];
                        hh[i] = h; ll[i] = (_Float16)(acc[i] - (float)h);
                    }
                    _Float16* Yt = (_Float16*)(lds_raw + t * ARENA + OFF_YT);
                    *(half4*)(Yt + cp * 136 + 16 * mi + 4 * q) = hh;
                    *(half4*)(Yt + cp * 136 + 64 + 16 * mi + 4 * q) = ll;
                }
            }
        }
    }
    __syncthreads();

    // ---- S2: streams; table loaded once per position, both batches consume
    for (int pos = wid; pos < 25; pos += 16) {
        const int mi = pos / 5, ni = pos - 5 * mi;
        const _Float16* ta = tbH + H_TA2 + mi * 2048 + lane8;
        half8 Ah0 = *(const half8*)(ta);
        half8 Al0 = *(const half8*)(ta + 512);
        half8 Ah1 = *(const half8*)(ta + 1024);
        half8 Al1 = *(const half8*)(ta + 1536);
        const int yoff = (16 * ni + n16) * 136 + 8 * q;
        const int cp = 16 * ni + n16;
        const int cc = (ni == 4) ? 32 : (cp & 31);
        const int isS = (ni == 4) ? n16 : (ni >> 1);
        const bool valid = (ni < 4) || (n16 < 2);
        #pragma unroll
        for (int t = 0; t < NB; t++) {
            const _Float16* Yt = (const _Float16*)(lds_raw + t * ARENA + OFF_YT);
            const _Float16* yrow = Yt + yoff;
            half8 Bh0 = *(const half8*)(yrow);
            half8 Bl0 = *(const half8*)(yrow + 64);
            half8 Bh1 = *(const half8*)(yrow + 32);
            half8 Bl1 = *(const half8*)(yrow + 96);
            floatx4 acc = {0.f, 0.f, 0.f, 0.f};
            acc = MFMA16(Ah0, Bh0, acc); acc = MFMA16(Ah0, Bl0, acc); acc = MFMA16(Al0, Bh0, acc);
            acc = MFMA16(Ah1, Bh1, acc); acc = MFMA16(Ah1, Bl1, acc); acc = MFMA16(Al1, Bh1, acc);
            if (valid) {
                _Float16* ST = (_Float16*)(lds_raw + t * ARENA + OFF_ST);
                float* S32 = (float*)(lds_raw + t * ARENA + OFF_S32);
                if (mi < 4) {
                    const int isQ = mi >> 1;
                    const int sid = isQ ? (isS ? 3 : 1) : (isS ? 2 : 0);
                    const int jjb = 16 * (mi & 1) + 4 * q;
                    floatx4 Sv = *(const floatx4*)(SegA[t] + cc * 32 + jjb);
                    float ssg = (sid == 2) ? -2.0f : 2.0f;
                    half4 hh, ll;
                    #pragma unroll
                    for (int i = 0; i < 4; i++) {
                        float v = ssg * Sv[i] * acc[i];
                        _Float16 h = (_Float16)v;
                        hh[i] = h; ll[i] = (_Float16)(v - (float)h);
                    }
                    _Float16* sb = ST + sid * 2376 + cc * 72 + jjb;
                    *(half4*)sb = hh;
                    *(half4*)(sb + 32) = ll;
                } else if (q == 0) {            // rows 64 (P32) / 65 (Q32) -> S32
                    float S = Se3A[t][cc];
                    #pragma unroll
                    for (int i = 0; i < 2; i++) {
                        int sid = i ? (isS ? 3 : 1) : (isS ? 2 : 0);
                        float v = 2.0f * S * acc[i];
                        if (sid == 2) v = -v;
                        S32[sid * 36 + cc] = v;
                    }
                }
            }
        }
    }
    __syncthreads();

    // ---- j=0 fixup: wave t handles batch t, lanes 0..32
    if (wid < NB && lane < 33) {
        _Float16* ST = (_Float16*)(lds_raw + wid * ARENA + OFF_ST);
        const int c = lane;
        float v0[4];
        #pragma unroll
        for (int sid = 0; sid < 4; sid++)
            v0[sid] = (float)ST[sid * 2376 + c * 72] + (float)ST[sid * 2376 + c * 72 + 32];
        float pr = 0.5f * (v0[0] + v0[3]), pi = 0.5f * (v0[1] + v0[2]);
        if (c == 0) { pr = 0.f; pi = 0.f; }
        float outs[4] = {pr, pi, pi, pr};
        #pragma unroll
        for (int sid = 0; sid < 4; sid++) {
            _Float16 h = (_Float16)outs[sid];
            ST[sid * 2376 + c * 72] = h;
            ST[sid * 2376 + c * 72 + 32] = (_Float16)(outs[sid] - (float)h);
        }
    }
    __syncthreads();

    // ---- S4a: 18 shared positions (ci, si, g); tables shared across batches
    for (int pos = wid; pos < 18; pos += 16) {
        const int ci = pos / 6, rem = pos - 6 * ci;
        const int si = rem >> 1, g = rem & 1;
        const _Float16* tg = tbH + H_TG + si * 2048 + lane8;
        half8 Grh = *(const half8*)(tg);
        half8 Grl = *(const half8*)(tg + 512);
        half8 Gih = *(const half8*)(tg + 1024);
        half8 Gil = *(const half8*)(tg + 1536);
        const int s = 16 * si + n16;
        const float ga = tf[F_GR32 + s], gi2 = tf[F_GI32 + s];
        const bool sval = (si < 2) || (n16 == 0);     // s <= 32
        const float sgn = g ? 1.0f : -1.0f;
        const int cb = 16 * ci + 4 * q;
        const int aoff = (2 * g) * 2376 + (16 * ci + n16) * 72 + 8 * q;
        #pragma unroll
        for (int t = 0; t < NB; t++) {
            const _Float16* ST = (const _Float16*)(lds_raw + t * ARENA + OFF_ST);
            const float* S32 = (const float*)(lds_raw + t * ARENA + OFF_S32);
            const _Float16* st0 = ST + aoff;
            half8 A0h = *(const half8*)(st0),        A0l = *(const half8*)(st0 + 32);
            half8 A1h = *(const half8*)(st0 + 2376), A1l = *(const half8*)(st0 + 2376 + 32);
            floatx4 aA = {0.f,0.f,0.f,0.f}, aB = aA;
            aA = MFMA16(A0h, Grh, aA); aA = MFMA16(A0h, Grl, aA); aA = MFMA16(A0l, Grh, aA);
            aB = MFMA16(A1h, Gih, aB); aB = MFMA16(A1h, Gil, aB); aB = MFMA16(A1l, Gih, aB);
            _Float16* Xo = (_Float16*)(lds_raw + t * ARENA + (g ? OFF_XI : OFF_XR));
            float* X32o = (float*)(lds_raw + t * ARENA + (g ? OFF_X32I : OFF_X32R));
            if (ci < 2) {
                floatx4 U0 = *(const floatx4*)(S32 + (2 * g) * 36 + cb);
                floatx4 U1 = *(const floatx4*)(S32 + (2 * g + 1) * 36 + cb);
                half4 hP, lP, hM, lM;
                #pragma unroll
                for (int i = 0; i < 4; i++) {
                    float av = aA[i] + ga * U0[i], bv = aB[i] + gi2 * U1[i];
                    float xP = av + sgn * bv;
                    float xM = av - sgn * bv;
                    _Float16 h;
                    h = (_Float16)xP; hP[i] = h; lP[i] = (_Float16)(xP - (float)h);
                    h = (_Float16)xM; hM[i] = h; lM[i] = (_Float16)(xM - (float)h);
                }
                if (sval) {
                    *(half4*)(Xo + s * 72 + cb) = hP;  *(half4*)(Xo + s * 72 + 32 + cb) = lP;
                    if (s >= 2) {
                        int sm = 65 - s;
                        *(half4*)(Xo + sm * 72 + cb) = hM;  *(half4*)(Xo + sm * 72 + 32 + cb) = lM;
                    }
                }
            } else if (q == 0 && sval) {            // c = 32 column -> fp32
                float u0 = S32[(2 * g) * 36 + 32], u1 = S32[(2 * g + 1) * 36 + 32];
                float av = aA[0] + ga * u0, bv = aB[0] + gi2 * u1;
                X32o[s] = av + sgn * bv;
                if (s >= 2) X32o[65 - s] = av - sgn * bv;
            }
        }
    }
    __syncthreads();

    // ---- S4b: 24 single-batch positions
    for (int p24 = wid; p24 < 24; p24 += 16) {
        const int t = p24 / 12;
        const int pos = p24 - 12 * t;
        const int ri = pos / 3, pti = pos - 3 * ri;
        const char* base = lds_raw + t * ARENA;
        const _Float16* Xr = (const _Float16*)(base + OFF_XR);
        const _Float16* Xi = (const _Float16*)(base + OFF_XI);
        const float* X32r = (const float*)(base + OFF_X32R);
        const float* X32i = (const float*)(base + OFF_X32I);
        float* psiT = (float*)(base + OFF_PSIT);
        const int brow = (16 * ri + n16) * 72 + 8 * q;
        half8 Brh = *(const half8*)(Xr + brow), Brl = *(const half8*)(Xr + brow + 32);
        half8 Bih = *(const half8*)(Xi + brow), Bil = *(const half8*)(Xi + brow + 32);
        const _Float16* th = tbH + H_TH + pti * 2048 + lane8;
        half8 Hch = *(const half8*)(th);
        half8 Hcl = *(const half8*)(th + 512);
        half8 Hsh = *(const half8*)(th + 1024);
        half8 Hsl = *(const half8*)(th + 1536);
        floatx4 aE = {0.f,0.f,0.f,0.f}, aF = aE;
        aE = MFMA16(Hch, Brh, aE); aE = MFMA16(Hch, Brl, aE); aE = MFMA16(Hcl, Brh, aE);
        aF = MFMA16(Hsh, Bih, aF); aF = MFMA16(Hsh, Bil, aF); aF = MFMA16(Hsl, Bih, aF);
        const int r = 16 * ri + n16;
        float xr32 = X32r[r], xi32 = X32i[r];
        if (pti < 2) {
            const int pb = 16 * pti + 4 * q;
            floatx4 Hc4 = *(const floatx4*)(tf + F_HC32 + pb);
            floatx4 Hs4 = *(const floatx4*)(tf + F_HS32 + pb);
            float* pp = psiT + pb * 65 + r;
            float* pm = psiT + (65 - pb) * 65 + r;
            #pragma unroll
            for (int i = 0; i < 4; i++) {
                float E = aE[i] + xr32 * Hc4[i];
                float F = aF[i] + xi32 * Hs4[i];
                pp[i * 65] = E - F;
                if (pb + i >= 2) pm[-i * 65] = E + F;
            }
        } else if (q == 0) {                    // p == 32
            float E = aE[0] + xr32 * tf[F_HC32 + 32];
            float F = aF[0] + xi32 * tf[F_HS32 + 32];
            psiT[32 * 65 + r] = E - F;
            psiT[33 * 65 + r] = E + F;
        }
    }
    __syncthreads();

    // ---- stencil: both batches, lane=c, rows 4*wid..+3 each
    #pragma unroll
    for (int t = 0; t < NB; t++) {
        const float* psiT = (const float*)(lds_raw + t * ARENA + OFF_PSIT);
        const float* x0 = xA[t];
        const float inv12 = inv12A[t], invf = invfA[t];
        const int c = lane;
        const int cm1 = (c + 63) & 63, cp1 = (c + 1) & 63;
        const int r0 = wid * 4;
        const float* xL = x0 + r0 * 64 + cm1;
        const float* xC = x0 + r0 * 64 + c;
        const float* xR = x0 + r0 * 64 + cp1;
        const float* pL = psiT + cm1 * 65 + r0;
        const float* pC = psiT + c * 65 + r0;
        const float* pR = psiT + cp1 * 65 + r0;
        float* ob = outA[t] + r0 * 64 + c;
        const int mo = (wid == 0) ? 63 : -1;    // prev-row offset (wraps for wid 0)
        float xLm = xL[mo * 64], xCm = xC[mo * 64], xRm = xR[mo * 64];
        float pLm = pL[mo], pCm = pC[mo], pRm = pR[mo];
        float xLc = xL[0], xCc = xC[0], xRc = xR[0];
        float pLc = pL[0], pCc = pC[0], pRc = pR[0];
        #pragma unroll
        for (int it = 0; it < 4; it++) {
            int ro = it + 1;
            if (it == 3 && wid == 15) ro = -60; // next-row wrap (uniform, last iter only)
            float xLp = xL[ro * 64], xCp = xC[ro * 64], xRp = xR[ro * 64];
            float pLp = pL[ro], pCp = pC[ro], pRp = pR[ro];
            float J1 = (pCp - pCm) * (xRc - xLc) - (pRc - pLc) * (xCp - xCm);
            float J2 = xRc * (pRp - pRm) - xLc * (pLp - pLm) - xCp * (pRp - pLp) + xCm * (pRm - pLm);
            float J3 = xRp * (pCp - pRc) - xLm * (pLc - pCm) - xLp * (pCp - pLc) + xRm * (pRc - pCm);
            float lap = xCm + xLc - 4.f * xCc + xRc + xLp + xCp;
            ob[it * 64] = -(J1 + J2 + J3) * inv12 + lap * invf;
            xLm = xLc; xCm = xCc; xRm = xRc; pLm = pLc; pCm = pCc; pRm = pRc;
            xLc = xLp; xCc = xCp; xRc = xRp; pLc = pLp; pCc = pCp; pRc = pRp;
        }
    }
}

extern "C" void kernel_launch(void* const* d_in, const int* in_sizes, int n_in,
                              void* d_out, int out_size, void* d_ws, size_t ws_size,
                              hipStream_t stream) {
    const float* y0     = (const float*)d_in[1];
    const int*   env    = (const int*)d_in[2];
    const float* params = (const float*)d_in[4];
    const float* domain = (const float*)d_in[5];
    float* out = (float*)d_out;
    float* ws  = (float*)d_ws;   // 101,152 B used

    setup_tables<<<dim3(163), dim3(256), 0, stream>>>(ws, domain);
    turb_kernel<<<dim3(2048), dim3(1024), 0, stream>>>(y0, env, params, domain, ws, out);
}

// Round 9
// 198.806 us; speedup vs baseline: 1.0233x; 1.0233x over previous
//
#include <hip/hip_runtime.h>
#include <math.h>

// Turb2dPDE, MFMA fp16-split pipeline. Per batch:
//   Y = x * C2; Out = F1 * Y; X = streams x G; psiT = Hc x X; then stencil.
// R1: 512-thread blocks.  R2/R3: SGPR addressing, const-offset stencil.
// R4: S32 restride->b128, Se dwordx4 layout.
// R6: NB=2 batches/block (grid 2048, LDS 80896, 2 blocks/CU): 99->90us.
// R7 (NB=4, 1 blk/CU) 110us; R8 (16-wave blocks) 122us -> R6 structure is the
//   scheduling optimum: 8-wave blocks, 2 blocks/CU, drains overlap across blocks.
// R9: critical-path cuts inside R6's structure:
//   - S1/S2/S4a imbalance fixed by splitting the odd position by batch
//     (S1 cp 6->5, S2 8->7, S4a 6->5 batch-units);
//   - j=0 fixup folded into S4a's A-fragment read (in-register patch on q==0
//     lanes) -> fixup barrier deleted (5->4 barriers/block), ST stays raw.

typedef _Float16 half8 __attribute__((ext_vector_type(8)));
typedef _Float16 half4 __attribute__((ext_vector_type(4)));
typedef float floatx4 __attribute__((ext_vector_type(4)));

#define WPI 0.09666439165562847f   // 2*pi/65

// half-unit offsets in ws
#define H_TB1 0        // [20 chunks][512] S1-B
#define H_TA2 10240    // [20 chunks][512] S2-A
#define H_TG  20480    // [12 chunks][512] S4a-B
#define H_TH  26624    // [12 chunks][512] S4b-A
// float-unit offsets
#define F_GR32 16384
#define F_GI32 16432
#define F_HC32 16480
#define F_HS32 16528
#define F_SE   16576   // [8][33] jj=32 col, then [8][33][32] grid
#define F_SEG  (F_SE + 264)

// per-batch LDS arena offsets (bytes), arena t at lds_raw + t*40448
#define ARENA 40448
#define NB 2
#define OFF_YT   0
#define OFF_XR   0
#define OFF_XI   9216
#define OFF_X32R 18432
#define OFF_X32I 18688
#define OFF_ST   18944
#define OFF_S32  37952      // [4][36] f32
#define OFF_PSIT 18944

__device__ __forceinline__ float trig65(int t, int isSin) {
    return isSin ? __sinf(WPI * (float)t) : __cosf(WPI * (float)t);
}

__global__ void setup_tables(float* __restrict__ ws, const float* __restrict__ domain) {
    int idx = blockIdx.x * 256 + threadIdx.x;
    _Float16* tbH = (_Float16*)ws;
    const float inv = 1.0f / 4225.0f;
    if (idx < 32768) {
        float v = 0.0f;
        int part;
        if (idx < 10240) {                  // TB1 (B-layout): chunk=(ni*2+kc)*2+part
            int chunk = idx >> 9, within = idx & 511;
            part = chunk & 1; int kc = (chunk >> 1) & 1, ni = chunk >> 2;
            int l2 = within >> 3, j = within & 7;
            int row = 16 * ni + (l2 & 15);
            int k = 32 * kc + 8 * (l2 >> 4) + j;
            if (row < 66) {
                int c = (row < 32) ? row : (row < 64 ? row - 32 : 32);
                int isS = (row < 32) ? 0 : (row < 64 ? 1 : row - 64);
                v = trig65((k * c) % 65, isS);
                if (k == 0) v += trig65((64 * c) % 65, isS);
            }
        } else if (idx < 20480) {           // TA2 (A-layout): chunk=(mi*2+kc)*2+part
            int i2 = idx - 10240;
            int chunk = i2 >> 9, within = i2 & 511;
            part = chunk & 1; int kc = (chunk >> 1) & 1, mi = chunk >> 2;
            int l2 = within >> 3, j = within & 7;
            int row = 16 * mi + (l2 & 15);
            int m = 32 * kc + 8 * (l2 >> 4) + j;
            if (row < 66) {
                int jr = (row < 32) ? row : (row < 64 ? row - 32 : 32);
                int isS = (row < 32) ? 0 : (row < 64 ? 1 : row - 64);
                float s = isS ? 1.0f : -1.0f;   // P rows = -cos, Q rows = +sin
                v = s * trig65((jr * m) % 65, isS);
                if (m == 0) v += s * trig65((jr * 64) % 65, isS);
            }
        } else if (idx < 26624) {           // TG: chunk=(si*2+g)*2+part
            int i2 = idx - 20480;
            int chunk = i2 >> 9, within = i2 & 511;
            part = chunk & 1; int g = (chunk >> 1) & 1, si = chunk >> 2;
            int l2 = within >> 3, j = within & 7;
            int s = 16 * si + (l2 & 15);
            int jj = 8 * (l2 >> 4) + j;
            if (s <= 32) v = trig65((s * jj) % 65, g);
        } else {                            // TH: chunk=(pi*2+h)*2+part
            int i2 = idx - 26624;
            int chunk = i2 >> 9, within = i2 & 511;
            part = chunk & 1; int h = (chunk >> 1) & 1, pi2 = chunk >> 2;
            int l2 = within >> 3, j = within & 7;
            int p = 16 * pi2 + (l2 & 15);
            int c = 8 * (l2 >> 4) + j;
            if (p <= 32) {
                if (c == 0) v = h ? 0.0f : inv;
                else v = 2.0f * inv * trig65((c * p) % 65, h);
            }
        }
        _Float16 hh = (_Float16)v;
        tbH[idx] = part ? (_Float16)(v - (float)hh) : hh;
    } else if (idx < 32960) {               // fp32 aux
        int i2 = idx - 32768;
        int grp = i2 / 48, s = i2 - grp * 48;
        float v = 0.0f;
        if (s <= 32) {
            int t = (32 * s) % 65;
            float cs = __cosf(WPI * t), sn = __sinf(WPI * t);
            v = (grp == 0) ? cs : (grp == 1) ? sn : (grp == 2) ? 2.0f * inv * cs : 2.0f * inv * sn;
        }
        ws[F_GR32 + i2] = v;
    } else if (idx < 41672) {               // Se
        int i2 = idx - 32960;
        const float DX0 = 0.04908738521234052f;
        int e2, a, b2;
        if (i2 < 264) { e2 = i2 / 33; a = i2 - e2 * 33; b2 = 32; }
        else {
            int i3 = i2 - 264;
            e2 = i3 / 1056;
            int rem = i3 - e2 * 1056;
            a = rem >> 5; b2 = rem & 31;
        }
        float fdx = domain[e2] * DX0;
        float tt = 6.283185307179586f / (65.0f * fdx);
        float s2v = tt * tt;
        ws[F_SE + i2] = -1.0f / (1e-12f + s2v * (float)(a * a + b2 * b2));
    }
}

#define MFMA16(A, B, C) __builtin_amdgcn_mfma_f32_16x16x32_f16((A), (B), (C), 0, 0, 0)

__global__ __launch_bounds__(512, 2)
void turb_kernel(const float* __restrict__ y0, const int* __restrict__ env,
                 const float* __restrict__ params, const float* __restrict__ domain,
                 const float* __restrict__ ws, float* __restrict__ out) {
    __shared__ __align__(16) char lds_raw[NB * ARENA];   // 80896 B -> 2 blocks/CU

    const int b0 = blockIdx.x * NB, tid = threadIdx.x;
    const int wid = __builtin_amdgcn_readfirstlane(tid >> 6);
    const int lane = tid & 63, n16 = lane & 15, q = lane >> 4;
    const int lane8 = lane * 8;
    const _Float16* tbH = (const _Float16*)ws;
    const float* tf = ws;

    // per-batch scalars
    int eA[NB];
    const float *SegA[NB], *Se3A[NB], *xA[NB];
    float* outA[NB];
    float invfA[NB], inv12A[NB];
    const float DX0 = 0.04908738521234052f;
    #pragma unroll
    for (int t = 0; t < NB; t++) {
        eA[t] = __builtin_amdgcn_readfirstlane(env[b0 + t]);
        SegA[t] = tf + F_SEG + eA[t] * 1056;
        Se3A[t] = tf + F_SE + eA[t] * 33;
        xA[t]   = y0 + (size_t)(b0 + t) * 4096;
        outA[t] = out + (size_t)(b0 + t) * 4096;
        float mu = params[2 * eA[t]];
        float f = domain[eA[t]] * DX0, f2 = f * f;
        inv12A[t] = 1.0f / (12.0f * f2);
        invfA[t] = mu / f2;
    }

    // ---- S1: Yt[c'][m] = sum_k x[m][k]*TB1[c'][k]
    // Waves 0-3: ni {0,1} both batches + (ni=2, t=0).
    // Waves 4-7: ni {3,4} both batches + (ni=2, t=1) (same mi fragments).
    {
        const int mi = wid & 3;
        const int hi = wid >> 2;
        half8 Ah[NB][2], Al[NB][2];
        #pragma unroll
        for (int t = 0; t < NB; t++) {
            const float* xrow = xA[t] + (16 * mi + n16) * 64 + 8 * q;
            #pragma unroll
            for (int kc = 0; kc < 2; kc++) {
                float4 v0 = *(const float4*)(xrow + 32 * kc);
                float4 v1 = *(const float4*)(xrow + 32 * kc + 4);
                float vv[8] = {v0.x, v0.y, v0.z, v0.w, v1.x, v1.y, v1.z, v1.w};
                #pragma unroll
                for (int u = 0; u < 8; u++) {
                    _Float16 h = (_Float16)vv[u];
                    Ah[t][kc][u] = h; Al[t][kc][u] = (_Float16)(vv[u] - (float)h);
                }
            }
        }
        half8 B0h, B0l, B1h, B1l;
        int cp; bool st;
        auto s1_pos = [&](int ni) {
            const _Float16* tb = tbH + H_TB1 + ni * 2048 + lane8;
            B0h = *(const half8*)(tb);
            B0l = *(const half8*)(tb + 512);
            B1h = *(const half8*)(tb + 1024);
            B1l = *(const half8*)(tb + 1536);
            cp = 16 * ni + n16;
            st = (ni < 4 || n16 < 2);
        };
        auto s1_body = [&](int t) {
            floatx4 acc = {0.f, 0.f, 0.f, 0.f};
            acc = MFMA16(Ah[t][0], B0h, acc); acc = MFMA16(Ah[t][0], B0l, acc); acc = MFMA16(Al[t][0], B0h, acc);
            acc = MFMA16(Ah[t][1], B1h, acc); acc = MFMA16(Ah[t][1], B1l, acc); acc = MFMA16(Al[t][1], B1h, acc);
            if (st) {
                half4 hh, ll;
                #pragma unroll
                for (int i = 0; i < 4; i++) {
                    _Float16 h = (_Float16)acc[i];
                    hh[i] = h; ll[i] = (_Float16)(acc[i] - (float)h);
                }
                _Float16* Yt = (_Float16*)(lds_raw + t * ARENA + OFF_YT);
                *(half4*)(Yt + cp * 136 + 16 * mi + 4 * q) = hh;
                *(half4*)(Yt + cp * 136 + 64 + 16 * mi + 4 * q) = ll;
            }
        };
        const int niBeg = hi ? 3 : 0;
        #pragma unroll
        for (int kk = 0; kk < 2; kk++) {
            s1_pos(niBeg + kk);
            s1_body(0); s1_body(1);
        }
        s1_pos(2);
        s1_body(hi);            // split position: t = hi
    }
    __syncthreads();

    // ---- S2: streams; positions 0..23 = wid+8k (both batches); pos 24 split
    // by batch across waves 0/1. Tables loaded once per position.
    {
        half8 Ah0, Al0, Ah1, Al1;
        int mi, ni, cc, isS, yoff; bool valid;
        auto s2_pos = [&](int pos) {
            mi = pos / 5; ni = pos - 5 * mi;
            const _Float16* ta = tbH + H_TA2 + mi * 2048 + lane8;
            Ah0 = *(const half8*)(ta);
            Al0 = *(const half8*)(ta + 512);
            Ah1 = *(const half8*)(ta + 1024);
            Al1 = *(const half8*)(ta + 1536);
            yoff = (16 * ni + n16) * 136 + 8 * q;
            int cp = 16 * ni + n16;
            cc = (ni == 4) ? 32 : (cp & 31);
            isS = (ni == 4) ? n16 : (ni >> 1);
            valid = (ni < 4) || (n16 < 2);
        };
        auto s2_body = [&](int t) {
            const _Float16* Yt = (const _Float16*)(lds_raw + t * ARENA + OFF_YT);
            const _Float16* yrow = Yt + yoff;
            half8 Bh0 = *(const half8*)(yrow);
            half8 Bl0 = *(const half8*)(yrow + 64);
            half8 Bh1 = *(const half8*)(yrow + 32);
            half8 Bl1 = *(const half8*)(yrow + 96);
            floatx4 acc = {0.f, 0.f, 0.f, 0.f};
            acc = MFMA16(Ah0, Bh0, acc); acc = MFMA16(Ah0, Bl0, acc); acc = MFMA16(Al0, Bh0, acc);
            acc = MFMA16(Ah1, Bh1, acc); acc = MFMA16(Ah1, Bl1, acc); acc = MFMA16(Al1, Bh1, acc);
            if (valid) {
                _Float16* ST = (_Float16*)(lds_raw + t * ARENA + OFF_ST);
                float* S32 = (float*)(lds_raw + t * ARENA + OFF_S32);
                if (mi < 4) {
                    const int isQ = mi >> 1;
                    const int sid = isQ ? (isS ? 3 : 1) : (isS ? 2 : 0);
                    const int jjb = 16 * (mi & 1) + 4 * q;
                    floatx4 Sv = *(const floatx4*)(SegA[t] + cc * 32 + jjb);
                    float ssg = (sid == 2) ? -2.0f : 2.0f;
                    half4 hh, ll;
                    #pragma unroll
                    for (int i = 0; i < 4; i++) {
                        float v = ssg * Sv[i] * acc[i];
                        _Float16 h = (_Float16)v;
                        hh[i] = h; ll[i] = (_Float16)(v - (float)h);
                    }
                    _Float16* sb = ST + sid * 2376 + cc * 72 + jjb;
                    *(half4*)sb = hh;
                    *(half4*)(sb + 32) = ll;
                } else if (q == 0) {            // rows 64 (P32) / 65 (Q32) -> S32
                    float S = Se3A[t][cc];
                    #pragma unroll
                    for (int i = 0; i < 2; i++) {
                        int sid = i ? (isS ? 3 : 1) : (isS ? 2 : 0);
                        float v = 2.0f * S * acc[i];
                        if (sid == 2) v = -v;
                        S32[sid * 36 + cc] = v;
                    }
                }
            }
        };
        #pragma unroll
        for (int k = 0; k < 3; k++) {
            s2_pos(wid + 8 * k);
            s2_body(0); s2_body(1);
        }
        if (wid < 2) {
            s2_pos(24);
            s2_body(wid);       // split position: t = wid
        }
    }
    __syncthreads();

    // ---- S4a with folded j=0 fixup. Positions 0..15 = wid+8k (both batches);
    // positions 16/17 split by batch across waves 0..3. ST stays raw; the
    // fixup (pr/pi from the 4 raw j=0 stream values) is applied in-register
    // to element 0 of the A-fragments on q==0 lanes.
    {
        half8 Grh, Grl, Gih, Gil;
        int ci, si, g, s, cb, aoff; float ga, gi2, sgn; bool sval;
        auto s4a_pos = [&](int pos) {
            ci = pos / 6; int rem = pos - 6 * ci;
            si = rem >> 1; g = rem & 1;
            const _Float16* tg = tbH + H_TG + si * 2048 + lane8;
            Grh = *(const half8*)(tg);
            Grl = *(const half8*)(tg + 512);
            Gih = *(const half8*)(tg + 1024);
            Gil = *(const half8*)(tg + 1536);
            s = 16 * si + n16;
            ga = tf[F_GR32 + s]; gi2 = tf[F_GI32 + s];
            sval = (si < 2) || (n16 == 0);     // s <= 32
            sgn = g ? 1.0f : -1.0f;
            cb = 16 * ci + 4 * q;
            aoff = (2 * g) * 2376 + (16 * ci + n16) * 72 + 8 * q;
        };
        auto s4a_body = [&](int t) {
            const _Float16* ST = (const _Float16*)(lds_raw + t * ARENA + OFF_ST);
            const float* S32 = (const float*)(lds_raw + t * ARENA + OFF_S32);
            const _Float16* st0 = ST + aoff;
            half8 A0h = *(const half8*)(st0),        A0l = *(const half8*)(st0 + 32);
            half8 A1h = *(const half8*)(st0 + 2376), A1l = *(const half8*)(st0 + 2376 + 32);
            if (q == 0) {                       // folded j=0 fixup patch
                const int cA = 16 * ci + n16;   // A-fragment row (c); >32 rows feed discarded outputs
                const int co = cA * 72;
                float v0 = (float)ST[co]            + (float)ST[co + 32];
                float v1 = (float)ST[2376 + co]     + (float)ST[2376 + co + 32];
                float v2 = (float)ST[4752 + co]     + (float)ST[4752 + co + 32];
                float v3 = (float)ST[7128 + co]     + (float)ST[7128 + co + 32];
                float pr = 0.5f * (v0 + v3), pi = 0.5f * (v1 + v2);
                if (cA == 0) { pr = 0.f; pi = 0.f; }
                float w0 = g ? pi : pr;         // stream 2g   (sid 0 -> pr, sid 2 -> pi)
                float w1 = g ? pr : pi;         // stream 2g+1 (sid 1 -> pi, sid 3 -> pr)
                _Float16 h0 = (_Float16)w0;
                A0h[0] = h0; A0l[0] = (_Float16)(w0 - (float)h0);
                _Float16 h1 = (_Float16)w1;
                A1h[0] = h1; A1l[0] = (_Float16)(w1 - (float)h1);
            }
            floatx4 aA = {0.f,0.f,0.f,0.f}, aB = aA;
            aA = MFMA16(A0h, Grh, aA); aA = MFMA16(A0h, Grl, aA); aA = MFMA16(A0l, Grh, aA);
            aB = MFMA16(A1h, Gih, aB); aB = MFMA16(A1h, Gil, aB); aB = MFMA16(A1l, Gih, aB);
            _Float16* Xo = (_Float16*)(lds_raw + t * ARENA + (g ? OFF_XI : OFF_XR));
            float* X32o = (float*)(lds_raw + t * ARENA + (g ? OFF_X32I : OFF_X32R));
            if (ci < 2) {
                floatx4 U0 = *(const floatx4*)(S32 + (2 * g) * 36 + cb);
                floatx4 U1 = *(const floatx4*)(S32 + (2 * g + 1) * 36 + cb);
                half4 hP, lP, hM, lM;
                #pragma unroll
                for (int i = 0; i < 4; i++) {
                    float av = aA[i] + ga * U0[i], bv = aB[i] + gi2 * U1[i];
                    float xP = av + sgn * bv;
                    float xM = av - sgn * bv;
                    _Float16 h;
                    h = (_Float16)xP; hP[i] = h; lP[i] = (_Float16)(xP - (float)h);
                    h = (_Float16)xM; hM[i] = h; lM[i] = (_Float16)(xM - (float)h);
                }
                if (sval) {
                    *(half4*)(Xo + s * 72 + cb) = hP;  *(half4*)(Xo + s * 72 + 32 + cb) = lP;
                    if (s >= 2) {
                        int sm = 65 - s;
                        *(half4*)(Xo + sm * 72 + cb) = hM;  *(half4*)(Xo + sm * 72 + 32 + cb) = lM;
                    }
                }
            } else if (q == 0 && sval) {            // c = 32 column -> fp32
                float u0 = S32[(2 * g) * 36 + 32], u1 = S32[(2 * g + 1) * 36 + 32];
                float av = aA[0] + ga * u0, bv = aB[0] + gi2 * u1;
                X32o[s] = av + sgn * bv;
                if (s >= 2) X32o[65 - s] = av - sgn * bv;
            }
        };
        #pragma unroll
        for (int k = 0; k < 2; k++) {
            s4a_pos(wid + 8 * k);
            s4a_body(0); s4a_body(1);
        }
        if (wid < 4) {
            s4a_pos(16 + (wid >> 1));   // waves 0,1 -> pos 16; waves 2,3 -> pos 17
            s4a_body(wid & 1);          // t = wid&1
        }
    }
    __syncthreads();

    // ---- S4b: 24 single-batch positions, 3 per wave
    for (int p24 = wid; p24 < 24; p24 += 8) {
        const int t = p24 / 12;
        const int pos = p24 - 12 * t;
        const int ri = pos / 3, pti = pos - 3 * ri;
        const char* base = lds_raw + t * ARENA;
        const _Float16* Xr = (const _Float16*)(base + OFF_XR);
        const _Float16* Xi = (const _Float16*)(base + OFF_XI);
        const float* X32r = (const float*)(base + OFF_X32R);
        const float* X32i = (const float*)(base + OFF_X32I);
        float* psiT = (float*)(base + OFF_PSIT);
        const int brow = (16 * ri + n16) * 72 + 8 * q;
        half8 Brh = *(const half8*)(Xr + brow), Brl = *(const half8*)(Xr + brow + 32);
        half8 Bih = *(const half8*)(Xi + brow), Bil = *(const half8*)(Xi + brow + 32);
        const _Float16* th = tbH + H_TH + pti * 2048 + lane8;
        half8 Hch = *(const half8*)(th);
        half8 Hcl = *(const half8*)(th + 512);
        half8 Hsh = *(const half8*)(th + 1024);
        half8 Hsl = *(const half8*)(th + 1536);
        floatx4 aE = {0.f,0.f,0.f,0.f}, aF = aE;
        aE = MFMA16(Hch, Brh, aE); aE = MFMA16(Hch, Brl, aE); aE = MFMA16(Hcl, Brh, aE);
        aF = MFMA16(Hsh, Bih, aF); aF = MFMA16(Hsh, Bil, aF); aF = MFMA16(Hsl, Bih, aF);
        const int r = 16 * ri + n16;
        float xr32 = X32r[r], xi32 = X32i[r];
        if (pti < 2) {
            const int pb = 16 * pti + 4 * q;
            floatx4 Hc4 = *(const floatx4*)(tf + F_HC32 + pb);
            floatx4 Hs4 = *(const floatx4*)(tf + F_HS32 + pb);
            float* pp = psiT + pb * 65 + r;
            float* pm = psiT + (65 - pb) * 65 + r;
            #pragma unroll
            for (int i = 0; i < 4; i++) {
                float E = aE[i] + xr32 * Hc4[i];
                float F = aF[i] + xi32 * Hs4[i];
                pp[i * 65] = E - F;
                if (pb + i >= 2) pm[-i * 65] = E + F;
            }
        } else if (q == 0) {                    // p == 32
            float E = aE[0] + xr32 * tf[F_HC32 + 32];
            float F = aF[0] + xi32 * tf[F_HS32 + 32];
            psiT[32 * 65 + r] = E - F;
            psiT[33 * 65 + r] = E + F;
        }
    }
    __syncthreads();

    // ---- stencil: both batches, lane=c, rows 8*wid..+7 each
    #pragma unroll
    for (int t = 0; t < NB; t++) {
        const float* psiT = (const float*)(lds_raw + t * ARENA + OFF_PSIT);
        const float* x0 = xA[t];
        const float inv12 = inv12A[t], invf = invfA[t];
        const int c = lane;
        const int cm1 = (c + 63) & 63, cp1 = (c + 1) & 63;
        const int r0 = wid * 8;
        const float* xL = x0 + r0 * 64 + cm1;
        const float* xC = x0 + r0 * 64 + c;
        const float* xR = x0 + r0 * 64 + cp1;
        const float* pL = psiT + cm1 * 65 + r0;
        const float* pC = psiT + c * 65 + r0;
        const float* pR = psiT + cp1 * 65 + r0;
        float* ob = outA[t] + r0 * 64 + c;
        const int mo = (wid == 0) ? 63 : -1;    // prev-row offset (wraps for wid 0)
        float xLm = xL[mo * 64], xCm = xC[mo * 64], xRm = xR[mo * 64];
        float pLm = pL[mo], pCm = pC[mo], pRm = pR[mo];
        float xLc = xL[0], xCc = xC[0], xRc = xR[0];
        float pLc = pL[0], pCc = pC[0], pRc = pR[0];
        #pragma unroll
        for (int it = 0; it < 8; it++) {
            int ro = it + 1;
            if (it == 7 && wid == 7) ro = -56;  // next-row wrap (uniform, last iter only)
            float xLp = xL[ro * 64], xCp = xC[ro * 64], xRp = xR[ro * 64];
            float pLp = pL[ro], pCp = pC[ro], pRp = pR[ro];
            float J1 = (pCp - pCm) * (xRc - xLc) - (pRc - pLc) * (xCp - xCm);
            float J2 = xRc * (pRp - pRm) - xLc * (pLp - pLm) - xCp * (pRp - pLp) + xCm * (pRm - pLm);
            float J3 = xRp * (pCp - pRc) - xLm * (pLc - pCm) - xLp * (pCp - pLc) + xRm * (pRc - pCm);
            float lap = xCm + xLc - 4.f * xCc + xRc + xLp + xCp;
            ob[it * 64] = -(J1 + J2 + J3) * inv12 + lap * invf;
            xLm = xLc; xCm = xCc; xRm = xRc; pLm = pLc; pCm = pCc; pRm = pRc;
            xLc = xLp; xCc = xCp; xRc = xRp; pLc = pLp; pCc = pCp; pRc = pRp;
        }
    }
}

extern "C" void kernel_launch(void* const* d_in, const int* in_sizes, int n_in,
                              void* d_out, int out_size, void* d_ws, size_t ws_size,
                              hipStream_t stream) {
    const float* y0     = (const float*)d_in[1];
    const int*   env    = (const int*)d_in[2];
    const float* params = (const float*)d_in[4];
    const float* domain = (const float*)d_in[5];
    float* out = (float*)d_out;
    float* ws  = (float*)d_ws;   // 101,152 B used

    setup_tables<<<dim3(163), dim3(256), 0, stream>>>(ws, domain);
    turb_kernel<<<dim3(2048), dim3(512), 0, stream>>>(y0, env, params, domain, ws, out);
}

// Round 10
// 179.218 us; speedup vs baseline: 1.1351x; 1.1093x over previous
//
#include <hip/hip_runtime.h>
#include <math.h>

// Turb2dPDE, MFMA fp16-split pipeline. Per batch:
//   Y = x * C2; Out = F1 * Y; X = streams x G; psiT = Hc x X; then stencil.
// R1: 512-thread blocks.  R2/R3: SGPR addressing, const-offset stencil.
// R4: S32 restride->b128, Se dwordx4 layout.
// R6: NB=2 batches/block (grid 2048, LDS 80896, 2 blocks/CU): 99->90us.
// R7 (NB=4) 110us, R8 (16-wave) 122us, R9 (rebalance+fixup-fold, lambdas) 113us
//   (fold ran per-body -> VALUBusy 66%; lambdas hurt codegen).
// R10: R6 verbatim + wave REBALANCE ONLY (no fixup fold, no lambdas):
//   odd positions split by batch -- S1 ni=2 -> t=hi (6->5 units),
//   S2 pos24 -> t=wid on waves 0/1 (8->7), S4a pos16/17 -> waves 0-3 (6->5).
//   Dedicated j=0 fixup barrier kept exactly as R6.

typedef _Float16 half8 __attribute__((ext_vector_type(8)));
typedef _Float16 half4 __attribute__((ext_vector_type(4)));
typedef float floatx4 __attribute__((ext_vector_type(4)));

#define WPI 0.09666439165562847f   // 2*pi/65

// half-unit offsets in ws
#define H_TB1 0        // [20 chunks][512] S1-B
#define H_TA2 10240    // [20 chunks][512] S2-A
#define H_TG  20480    // [12 chunks][512] S4a-B
#define H_TH  26624    // [12 chunks][512] S4b-A
// float-unit offsets
#define F_GR32 16384
#define F_GI32 16432
#define F_HC32 16480
#define F_HS32 16528
#define F_SE   16576   // [8][33] jj=32 col, then [8][33][32] grid
#define F_SEG  (F_SE + 264)

// per-batch LDS arena offsets (bytes), arena t at lds_raw + t*40448
#define ARENA 40448
#define NB 2
#define OFF_YT   0
#define OFF_XR   0
#define OFF_XI   9216
#define OFF_X32R 18432
#define OFF_X32I 18688
#define OFF_ST   18944
#define OFF_S32  37952      // [4][36] f32
#define OFF_PSIT 18944

__device__ __forceinline__ float trig65(int t, int isSin) {
    return isSin ? __sinf(WPI * (float)t) : __cosf(WPI * (float)t);
}

__global__ void setup_tables(float* __restrict__ ws, const float* __restrict__ domain) {
    int idx = blockIdx.x * 256 + threadIdx.x;
    _Float16* tbH = (_Float16*)ws;
    const float inv = 1.0f / 4225.0f;
    if (idx < 32768) {
        float v = 0.0f;
        int part;
        if (idx < 10240) {                  // TB1 (B-layout): chunk=(ni*2+kc)*2+part
            int chunk = idx >> 9, within = idx & 511;
            part = chunk & 1; int kc = (chunk >> 1) & 1, ni = chunk >> 2;
            int l2 = within >> 3, j = within & 7;
            int row = 16 * ni + (l2 & 15);
            int k = 32 * kc + 8 * (l2 >> 4) + j;
            if (row < 66) {
                int c = (row < 32) ? row : (row < 64 ? row - 32 : 32);
                int isS = (row < 32) ? 0 : (row < 64 ? 1 : row - 64);
                v = trig65((k * c) % 65, isS);
                if (k == 0) v += trig65((64 * c) % 65, isS);
            }
        } else if (idx < 20480) {           // TA2 (A-layout): chunk=(mi*2+kc)*2+part
            int i2 = idx - 10240;
            int chunk = i2 >> 9, within = i2 & 511;
            part = chunk & 1; int kc = (chunk >> 1) & 1, mi = chunk >> 2;
            int l2 = within >> 3, j = within & 7;
            int row = 16 * mi + (l2 & 15);
            int m = 32 * kc + 8 * (l2 >> 4) + j;
            if (row < 66) {
                int jr = (row < 32) ? row : (row < 64 ? row - 32 : 32);
                int isS = (row < 32) ? 0 : (row < 64 ? 1 : row - 64);
                float s = isS ? 1.0f : -1.0f;   // P rows = -cos, Q rows = +sin
                v = s * trig65((jr * m) % 65, isS);
                if (m == 0) v += s * trig65((jr * 64) % 65, isS);
            }
        } else if (idx < 26624) {           // TG: chunk=(si*2+g)*2+part
            int i2 = idx - 20480;
            int chunk = i2 >> 9, within = i2 & 511;
            part = chunk & 1; int g = (chunk >> 1) & 1, si = chunk >> 2;
            int l2 = within >> 3, j = within & 7;
            int s = 16 * si + (l2 & 15);
            int jj = 8 * (l2 >> 4) + j;
            if (s <= 32) v = trig65((s * jj) % 65, g);
        } else {                            // TH: chunk=(pi*2+h)*2+part
            int i2 = idx - 26624;
            int chunk = i2 >> 9, within = i2 & 511;
            part = chunk & 1; int h = (chunk >> 1) & 1, pi2 = chunk >> 2;
            int l2 = within >> 3, j = within & 7;
            int p = 16 * pi2 + (l2 & 15);
            int c = 8 * (l2 >> 4) + j;
            if (p <= 32) {
                if (c == 0) v = h ? 0.0f : inv;
                else v = 2.0f * inv * trig65((c * p) % 65, h);
            }
        }
        _Float16 hh = (_Float16)v;
        tbH[idx] = part ? (_Float16)(v - (float)hh) : hh;
    } else if (idx < 32960) {               // fp32 aux
        int i2 = idx - 32768;
        int grp = i2 / 48, s = i2 - grp * 48;
        float v = 0.0f;
        if (s <= 32) {
            int t = (32 * s) % 65;
            float cs = __cosf(WPI * t), sn = __sinf(WPI * t);
            v = (grp == 0) ? cs : (grp == 1) ? sn : (grp == 2) ? 2.0f * inv * cs : 2.0f * inv * sn;
        }
        ws[F_GR32 + i2] = v;
    } else if (idx < 41672) {               // Se
        int i2 = idx - 32960;
        const float DX0 = 0.04908738521234052f;
        int e2, a, b2;
        if (i2 < 264) { e2 = i2 / 33; a = i2 - e2 * 33; b2 = 32; }
        else {
            int i3 = i2 - 264;
            e2 = i3 / 1056;
            int rem = i3 - e2 * 1056;
            a = rem >> 5; b2 = rem & 31;
        }
        float fdx = domain[e2] * DX0;
        float tt = 6.283185307179586f / (65.0f * fdx);
        float s2v = tt * tt;
        ws[F_SE + i2] = -1.0f / (1e-12f + s2v * (float)(a * a + b2 * b2));
    }
}

#define MFMA16(A, B, C) __builtin_amdgcn_mfma_f32_16x16x32_f16((A), (B), (C), 0, 0, 0)

__global__ __launch_bounds__(512, 4)
void turb_kernel(const float* __restrict__ y0, const int* __restrict__ env,
                 const float* __restrict__ params, const float* __restrict__ domain,
                 const float* __restrict__ ws, float* __restrict__ out) {
    __shared__ __align__(16) char lds_raw[NB * ARENA];   // 80896 B -> 2 blocks/CU

    const int b0 = blockIdx.x * NB, tid = threadIdx.x;
    const int wid = __builtin_amdgcn_readfirstlane(tid >> 6);
    const int lane = tid & 63, n16 = lane & 15, q = lane >> 4;
    const int lane8 = lane * 8;
    const _Float16* tbH = (const _Float16*)ws;
    const float* tf = ws;

    // per-batch scalars
    int eA[NB];
    const float *SegA[NB], *Se3A[NB], *xA[NB];
    float* outA[NB];
    float invfA[NB], inv12A[NB];
    const float DX0 = 0.04908738521234052f;
    #pragma unroll
    for (int t = 0; t < NB; t++) {
        eA[t] = __builtin_amdgcn_readfirstlane(env[b0 + t]);
        SegA[t] = tf + F_SEG + eA[t] * 1056;
        Se3A[t] = tf + F_SE + eA[t] * 33;
        xA[t]   = y0 + (size_t)(b0 + t) * 4096;
        outA[t] = out + (size_t)(b0 + t) * 4096;
        float mu = params[2 * eA[t]];
        float f = domain[eA[t]] * DX0, f2 = f * f;
        inv12A[t] = 1.0f / (12.0f * f2);
        invfA[t] = mu / f2;
    }

    // ---- S1: Yt[c'][m] = sum_k x[m][k]*TB1[c'][k]
    // Waves 0-3: ni {0,1} both batches; waves 4-7: ni {3,4} both batches;
    // shared position ni=2 split by batch: t = wid>>2. Max units 6 -> 5.
    {
        const int mi = wid & 3;
        const int hi = wid >> 2;
        half8 Ah[NB][2], Al[NB][2];
        #pragma unroll
        for (int t = 0; t < NB; t++) {
            const float* xrow = xA[t] + (16 * mi + n16) * 64 + 8 * q;
            #pragma unroll
            for (int kc = 0; kc < 2; kc++) {
                float4 v0 = *(const float4*)(xrow + 32 * kc);
                float4 v1 = *(const float4*)(xrow + 32 * kc + 4);
                float vv[8] = {v0.x, v0.y, v0.z, v0.w, v1.x, v1.y, v1.z, v1.w};
                #pragma unroll
                for (int u = 0; u < 8; u++) {
                    _Float16 h = (_Float16)vv[u];
                    Ah[t][kc][u] = h; Al[t][kc][u] = (_Float16)(vv[u] - (float)h);
                }
            }
        }
        #pragma unroll
        for (int k = 0; k < 3; k++) {
            const int ni = (k < 2) ? ((hi ? 3 : 0) + k) : 2;
            const int tSel = (k < 2) ? -1 : hi;
            const _Float16* tb = tbH + H_TB1 + ni * 2048 + lane8;
            half8 B0h = *(const half8*)(tb);
            half8 B0l = *(const half8*)(tb + 512);
            half8 B1h = *(const half8*)(tb + 1024);
            half8 B1l = *(const half8*)(tb + 1536);
            const int cp = 16 * ni + n16;
            const bool st = (ni < 4 || n16 < 2);
            #pragma unroll
            for (int t = 0; t < NB; t++) {
                if (tSel >= 0 && t != tSel) continue;
                floatx4 acc = {0.f, 0.f, 0.f, 0.f};
                acc = MFMA16(Ah[t][0], B0h, acc); acc = MFMA16(Ah[t][0], B0l, acc); acc = MFMA16(Al[t][0], B0h, acc);
                acc = MFMA16(Ah[t][1], B1h, acc); acc = MFMA16(Ah[t][1], B1l, acc); acc = MFMA16(Al[t][1], B1h, acc);
                if (st) {
                    half4 hh, ll;
                    #pragma unroll
                    for (int i = 0; i < 4; i++) {
                        _Float16 h = (_Float16)acc[i];
                        hh[i] = h; ll[i] = (_Float16)(acc[i] - (float)h);
                    }
                    _Float16* Yt = (_Float16*)(lds_raw + t * ARENA + OFF_YT);
                    *(half4*)(Yt + cp * 136 + 16 * mi + 4 * q) = hh;
                    *(half4*)(Yt + cp * 136 + 64 + 16 * mi + 4 * q) = ll;
                }
            }
        }
    }
    __syncthreads();

    // ---- S2: streams; positions wid+8k (k=0..2) both batches; pos 24 split
    // by batch across waves 0/1. Max units 8 -> 7.
    for (int k = 0; k < 4; k++) {
        int pos, tSel;
        if (k < 3) { pos = wid + 8 * k; tSel = -1; }
        else { if (wid >= 2) break; pos = 24; tSel = wid; }
        const int mi = pos / 5, ni = pos - 5 * mi;
        const _Float16* ta = tbH + H_TA2 + mi * 2048 + lane8;
        half8 Ah0 = *(const half8*)(ta);
        half8 Al0 = *(const half8*)(ta + 512);
        half8 Ah1 = *(const half8*)(ta + 1024);
        half8 Al1 = *(const half8*)(ta + 1536);
        const int yoff = (16 * ni + n16) * 136 + 8 * q;
        const int cp = 16 * ni + n16;
        const int cc = (ni == 4) ? 32 : (cp & 31);
        const int isS = (ni == 4) ? n16 : (ni >> 1);
        const bool valid = (ni < 4) || (n16 < 2);
        #pragma unroll
        for (int t = 0; t < NB; t++) {
            if (tSel >= 0 && t != tSel) continue;
            const _Float16* Yt = (const _Float16*)(lds_raw + t * ARENA + OFF_YT);
            const _Float16* yrow = Yt + yoff;
            half8 Bh0 = *(const half8*)(yrow);
            half8 Bl0 = *(const half8*)(yrow + 64);
            half8 Bh1 = *(const half8*)(yrow + 32);
            half8 Bl1 = *(const half8*)(yrow + 96);
            floatx4 acc = {0.f, 0.f, 0.f, 0.f};
            acc = MFMA16(Ah0, Bh0, acc); acc = MFMA16(Ah0, Bl0, acc); acc = MFMA16(Al0, Bh0, acc);
            acc = MFMA16(Ah1, Bh1, acc); acc = MFMA16(Ah1, Bl1, acc); acc = MFMA16(Al1, Bh1, acc);
            if (valid) {
                _Float16* ST = (_Float16*)(lds_raw + t * ARENA + OFF_ST);
                float* S32 = (float*)(lds_raw + t * ARENA + OFF_S32);
                if (mi < 4) {
                    const int isQ = mi >> 1;
                    const int sid = isQ ? (isS ? 3 : 1) : (isS ? 2 : 0);
                    const int jjb = 16 * (mi & 1) + 4 * q;
                    floatx4 Sv = *(const floatx4*)(SegA[t] + cc * 32 + jjb);
                    float ssg = (sid == 2) ? -2.0f : 2.0f;
                    half4 hh, ll;
                    #pragma unroll
                    for (int i = 0; i < 4; i++) {
                        float v = ssg * Sv[i] * acc[i];
                        _Float16 h = (_Float16)v;
                        hh[i] = h; ll[i] = (_Float16)(v - (float)h);
                    }
                    _Float16* sb = ST + sid * 2376 + cc * 72 + jjb;
                    *(half4*)sb = hh;
                    *(half4*)(sb + 32) = ll;
                } else if (q == 0) {            // rows 64 (P32) / 65 (Q32) -> S32
                    float S = Se3A[t][cc];
                    #pragma unroll
                    for (int i = 0; i < 2; i++) {
                        int sid = i ? (isS ? 3 : 1) : (isS ? 2 : 0);
                        float v = 2.0f * S * acc[i];
                        if (sid == 2) v = -v;
                        S32[sid * 36 + cc] = v;
                    }
                }
            }
        }
    }
    __syncthreads();

    // ---- j=0 fixup: wave t handles batch t, lanes 0..32 (exactly as R6)
    if (wid < NB && lane < 33) {
        _Float16* ST = (_Float16*)(lds_raw + wid * ARENA + OFF_ST);
        const int c = lane;
        float v0[4];
        #pragma unroll
        for (int sid = 0; sid < 4; sid++)
            v0[sid] = (float)ST[sid * 2376 + c * 72] + (float)ST[sid * 2376 + c * 72 + 32];
        float pr = 0.5f * (v0[0] + v0[3]), pi = 0.5f * (v0[1] + v0[2]);
        if (c == 0) { pr = 0.f; pi = 0.f; }
        float outs[4] = {pr, pi, pi, pr};
        #pragma unroll
        for (int sid = 0; sid < 4; sid++) {
            _Float16 h = (_Float16)outs[sid];
            ST[sid * 2376 + c * 72] = h;
            ST[sid * 2376 + c * 72 + 32] = (_Float16)(outs[sid] - (float)h);
        }
    }
    __syncthreads();

    // ---- S4a: positions wid+8k (k=0..1) both batches; pos 16/17 split by
    // batch across waves 0-3 (wave w -> pos 16+(w>>1), t = w&1). Max 6 -> 5.
    for (int k = 0; k < 3; k++) {
        int pos, tSel;
        if (k < 2) { pos = wid + 8 * k; tSel = -1; }
        else { if (wid >= 4) break; pos = 16 + (wid >> 1); tSel = wid & 1; }
        const int ci = pos / 6, rem = pos - 6 * ci;
        const int si = rem >> 1, g = rem & 1;
        const _Float16* tg = tbH + H_TG + si * 2048 + lane8;
        half8 Grh = *(const half8*)(tg);
        half8 Grl = *(const half8*)(tg + 512);
        half8 Gih = *(const half8*)(tg + 1024);
        half8 Gil = *(const half8*)(tg + 1536);
        const int s = 16 * si + n16;
        const float ga = tf[F_GR32 + s], gi2 = tf[F_GI32 + s];
        const bool sval = (si < 2) || (n16 == 0);     // s <= 32
        const float sgn = g ? 1.0f : -1.0f;
        const int cb = 16 * ci + 4 * q;
        const int aoff = (2 * g) * 2376 + (16 * ci + n16) * 72 + 8 * q;
        #pragma unroll
        for (int t = 0; t < NB; t++) {
            if (tSel >= 0 && t != tSel) continue;
            const _Float16* ST = (const _Float16*)(lds_raw + t * ARENA + OFF_ST);
            const float* S32 = (const float*)(lds_raw + t * ARENA + OFF_S32);
            const _Float16* st0 = ST + aoff;
            half8 A0h = *(const half8*)(st0),        A0l = *(const half8*)(st0 + 32);
            half8 A1h = *(const half8*)(st0 + 2376), A1l = *(const half8*)(st0 + 2376 + 32);
            floatx4 aA = {0.f,0.f,0.f,0.f}, aB = aA;
            aA = MFMA16(A0h, Grh, aA); aA = MFMA16(A0h, Grl, aA); aA = MFMA16(A0l, Grh, aA);
            aB = MFMA16(A1h, Gih, aB); aB = MFMA16(A1h, Gil, aB); aB = MFMA16(A1l, Gih, aB);
            _Float16* Xo = (_Float16*)(lds_raw + t * ARENA + (g ? OFF_XI : OFF_XR));
            float* X32o = (float*)(lds_raw + t * ARENA + (g ? OFF_X32I : OFF_X32R));
            if (ci < 2) {
                floatx4 U0 = *(const floatx4*)(S32 + (2 * g) * 36 + cb);
                floatx4 U1 = *(const floatx4*)(S32 + (2 * g + 1) * 36 + cb);
                half4 hP, lP, hM, lM;
                #pragma unroll
                for (int i = 0; i < 4; i++) {
                    float av = aA[i] + ga * U0[i], bv = aB[i] + gi2 * U1[i];
                    float xP = av + sgn * bv;
                    float xM = av - sgn * bv;
                    _Float16 h;
                    h = (_Float16)xP; hP[i] = h; lP[i] = (_Float16)(xP - (float)h);
                    h = (_Float16)xM; hM[i] = h; lM[i] = (_Float16)(xM - (float)h);
                }
                if (sval) {
                    *(half4*)(Xo + s * 72 + cb) = hP;  *(half4*)(Xo + s * 72 + 32 + cb) = lP;
                    if (s >= 2) {
                        int sm = 65 - s;
                        *(half4*)(Xo + sm * 72 + cb) = hM;  *(half4*)(Xo + sm * 72 + 32 + cb) = lM;
                    }
                }
            } else if (q == 0 && sval) {            // c = 32 column -> fp32
                float u0 = S32[(2 * g) * 36 + 32], u1 = S32[(2 * g + 1) * 36 + 32];
                float av = aA[0] + ga * u0, bv = aB[0] + gi2 * u1;
                X32o[s] = av + sgn * bv;
                if (s >= 2) X32o[65 - s] = av - sgn * bv;
            }
        }
    }
    __syncthreads();

    // ---- S4b: 24 single-batch positions, 3 per wave
    for (int p24 = wid; p24 < 24; p24 += 8) {
        const int t = p24 / 12;
        const int pos = p24 - 12 * t;
        const int ri = pos / 3, pti = pos - 3 * ri;
        const char* base = lds_raw + t * ARENA;
        const _Float16* Xr = (const _Float16*)(base + OFF_XR);
        const _Float16* Xi = (const _Float16*)(base + OFF_XI);
        const float* X32r = (const float*)(base + OFF_X32R);
        const float* X32i = (const float*)(base + OFF_X32I);
        float* psiT = (float*)(base + OFF_PSIT);
        const int brow = (16 * ri + n16) * 72 + 8 * q;
        half8 Brh = *(const half8*)(Xr + brow), Brl = *(const half8*)(Xr + brow + 32);
        half8 Bih = *(const half8*)(Xi + brow), Bil = *(const half8*)(Xi + brow + 32);
        const _Float16* th = tbH + H_TH + pti * 2048 + lane8;
        half8 Hch = *(const half8*)(th);
        half8 Hcl = *(const half8*)(th + 512);
        half8 Hsh = *(const half8*)(th + 1024);
        half8 Hsl = *(const half8*)(th + 1536);
        floatx4 aE = {0.f,0.f,0.f,0.f}, aF = aE;
        aE = MFMA16(Hch, Brh, aE); aE = MFMA16(Hch, Brl, aE); aE = MFMA16(Hcl, Brh, aE);
        aF = MFMA16(Hsh, Bih, aF); aF = MFMA16(Hsh, Bil, aF); aF = MFMA16(Hsl, Bih, aF);
        const int r = 16 * ri + n16;
        float xr32 = X32r[r], xi32 = X32i[r];
        if (pti < 2) {
            const int pb = 16 * pti + 4 * q;
            floatx4 Hc4 = *(const floatx4*)(tf + F_HC32 + pb);
            floatx4 Hs4 = *(const floatx4*)(tf + F_HS32 + pb);
            float* pp = psiT + pb * 65 + r;
            float* pm = psiT + (65 - pb) * 65 + r;
            #pragma unroll
            for (int i = 0; i < 4; i++) {
                float E = aE[i] + xr32 * Hc4[i];
                float F = aF[i] + xi32 * Hs4[i];
                pp[i * 65] = E - F;
                if (pb + i >= 2) pm[-i * 65] = E + F;
            }
        } else if (q == 0) {                    // p == 32
            float E = aE[0] + xr32 * tf[F_HC32 + 32];
            float F = aF[0] + xi32 * tf[F_HS32 + 32];
            psiT[32 * 65 + r] = E - F;
            psiT[33 * 65 + r] = E + F;
        }
    }
    __syncthreads();

    // ---- stencil: both batches, lane=c, rows 8*wid..+7 each
    #pragma unroll
    for (int t = 0; t < NB; t++) {
        const float* psiT = (const float*)(lds_raw + t * ARENA + OFF_PSIT);
        const float* x0 = xA[t];
        const float inv12 = inv12A[t], invf = invfA[t];
        const int c = lane;
        const int cm1 = (c + 63) & 63, cp1 = (c + 1) & 63;
        const int r0 = wid * 8;
        const float* xL = x0 + r0 * 64 + cm1;
        const float* xC = x0 + r0 * 64 + c;
        const float* xR = x0 + r0 * 64 + cp1;
        const float* pL = psiT + cm1 * 65 + r0;
        const float* pC = psiT + c * 65 + r0;
        const float* pR = psiT + cp1 * 65 + r0;
        float* ob = outA[t] + r0 * 64 + c;
        const int mo = (wid == 0) ? 63 : -1;    // prev-row offset (wraps for wid 0)
        float xLm = xL[mo * 64], xCm = xC[mo * 64], xRm = xR[mo * 64];
        float pLm = pL[mo], pCm = pC[mo], pRm = pR[mo];
        float xLc = xL[0], xCc = xC[0], xRc = xR[0];
        float pLc = pL[0], pCc = pC[0], pRc = pR[0];
        #pragma unroll
        for (int it = 0; it < 8; it++) {
            int ro = it + 1;
            if (it == 7 && wid == 7) ro = -56;  // next-row wrap (uniform, last iter only)
            float xLp = xL[ro * 64], xCp = xC[ro * 64], xRp = xR[ro * 64];
            float pLp = pL[ro], pCp = pC[ro], pRp = pR[ro];
            float J1 = (pCp - pCm) * (xRc - xLc) - (pRc - pLc) * (xCp - xCm);
            float J2 = xRc * (pRp - pRm) - xLc * (pLp - pLm) - xCp * (pRp - pLp) + xCm * (pRm - pLm);
            float J3 = xRp * (pCp - pRc) - xLm * (pLc - pCm) - xLp * (pCp - pLc) + xRm * (pRc - pCm);
            float lap = xCm + xLc - 4.f * xCc + xRc + xLp + xCp;
            ob[it * 64] = -(J1 + J2 + J3) * inv12 + lap * invf;
            xLm = xLc; xCm = xCc; xRm = xRc; pLm = pLc; pCm = pCc; pRm = pRc;
            xLc = xLp; xCc = xCp; xRc = xRp; pLc = pLp; pCc = pCp; pRc = pRp;
        }
    }
}

extern "C" void kernel_launch(void* const* d_in, const int* in_sizes, int n_in,
                              void* d_out, int out_size, void* d_ws, size_t ws_size,
                              hipStream_t stream) {
    const float* y0     = (const float*)d_in[1];
    const int*   env    = (const int*)d_in[2];
    const float* params = (const float*)d_in[4];
    const float* domain = (const float*)d_in[5];
    float* out = (float*)d_out;
    float* ws  = (float*)d_ws;   // 101,152 B used

    setup_tables<<<dim3(163), dim3(256), 0, stream>>>(ws, domain);
    turb_kernel<<<dim3(2048), dim3(512), 0, stream>>>(y0, env, params, domain, ws, out);
}